// Round 11
// baseline (1073.206 us; speedup 1.0000x reference)
//
#include <hip/hip_runtime.h>

// LSTM: B=256, T=8192, I=5, H=16, fc -> 1.  One wave per batch element,
// 256 blocks. R10 = 1027us (301 cyc/step), stall-dominated (VALU-busy time
// invariant under readlane<->bpermute swap).
// R11: split the h-broadcast by consumption order:
//   k=0..3  -> 4x f32 v_readlane + fma (short chain head, consumed first)
//   k=4..15 -> 6x ds_bpermute f16 pairs + dot2 (latency hidden, consumed last)
// Pack (quad_swap+cvt_pk) only feeds the bps now - off the chain head.
// Lessons: R4 update_dpp old-tie movs; R5 LDS-read broadcast latency in a
// short window; R6/R7 co-residency/2-seq interleave raise wall; R9 f16 dot2
// diet works; R10 stalls dominate, not issue.

typedef _Float16 half2v __attribute__((ext_vector_type(2)));
typedef __fp16   fp16x2 __attribute__((ext_vector_type(2)));

__device__ __forceinline__ float readlane_f(float v, int l) {
    return __int_as_float(__builtin_amdgcn_readlane(__float_as_int(v), l));
}
__device__ __forceinline__ half2v pk16(float a, float b) {
    union { fp16x2 f; half2v h; } cc;
    cc.f = __builtin_amdgcn_cvt_pkrtz(a, b);
    return cc.h;
}
__device__ __forceinline__ float dot2(half2v a, half2v b, float c) {
#if __has_builtin(__builtin_amdgcn_fdot2)
    return __builtin_amdgcn_fdot2(a, b, c, false);
#else
    return fmaf((float)a[0], (float)b[0], fmaf((float)a[1], (float)b[1], c));
#endif
}
// lane j -> value of lane j^1 (quad_perm [1,0,3,2] = 0xB1), single dpp mov.
__device__ __forceinline__ float quad_swap1(float v) {
    return __int_as_float(__builtin_amdgcn_update_dpp(
        0, __float_as_int(v), 0xB1, 0xF, 0xF, true));
}
__device__ __forceinline__ unsigned h2u(half2v h) {
    union { half2v h; unsigned u; } cc; cc.h = h; return cc.u;
}
__device__ __forceinline__ half2v u2h(unsigned u) {
    union { half2v h; unsigned u; } cc; cc.u = u; return cc.h;
}

__device__ __forceinline__ void plswap32(float& a, float& b) {
#if __has_builtin(__builtin_amdgcn_permlane32_swap)
    auto r = __builtin_amdgcn_permlane32_swap(__float_as_uint(a),
                                              __float_as_uint(b), false, false);
    a = __uint_as_float(r[0]);
    b = __uint_as_float(r[1]);
#else
    unsigned ao, bo;
    asm("v_mov_b32 %0, %2\n\t"
        "v_mov_b32 %1, %3\n\t"
        "v_permlane32_swap_b32 %0, %1"
        : "=&v"(ao), "=&v"(bo)
        : "v"(__float_as_uint(a)), "v"(__float_as_uint(b)));
    a = __uint_as_float(ao);
    b = __uint_as_float(bo);
#endif
}
__device__ __forceinline__ void plswap16(float& a, float& b) {
#if __has_builtin(__builtin_amdgcn_permlane16_swap)
    auto r = __builtin_amdgcn_permlane16_swap(__float_as_uint(a),
                                              __float_as_uint(b), false, false);
    a = __uint_as_float(r[0]);
    b = __uint_as_float(r[1]);
#else
    unsigned ao, bo;
    asm("v_mov_b32 %0, %2\n\t"
        "v_mov_b32 %1, %3\n\t"
        "v_permlane16_swap_b32 %0, %1"
        : "=&v"(ao), "=&v"(bo)
        : "v"(__float_as_uint(a)), "v"(__float_as_uint(b)));
    a = __uint_as_float(ao);
    b = __uint_as_float(bo);
#endif
}

__global__ __launch_bounds__(64, 1) void lstm_fused(
    const float* __restrict__ x,      // [B, T, 5]
    const float* __restrict__ W_ih,   // [64, 5]
    const float* __restrict__ W_hh,   // [64, 16]
    const float* __restrict__ b_ih,   // [64]
    const float* __restrict__ b_hh,   // [64]
    const float* __restrict__ fc_w,   // [1, 16]
    const float* __restrict__ fc_b,   // [1]
    float* __restrict__ out,          // [B, T]
    int T)
{
    const int lane = threadIdx.x;     // 0..63
    const int jj   = lane & 15;
    const int q    = lane >> 4;
    const bool isg = (q == 2);
    const int b    = blockIdx.x;

    const float LOG2E  = 1.4426950408889634f;
    const float KN2    = -2.0f * LOG2E;            // tanh(c) scale
    const float wscale = isg ? (-2.0f * LOG2E) : (-LOG2E);
    const float post_m = isg ?  2.0f : 1.0f;
    const float post_a = isg ? -1.0f : 0.0f;

    const float wi0 = W_ih[lane * 5 + 0] * wscale;
    const float wi1 = W_ih[lane * 5 + 1] * wscale;
    const float wi2 = W_ih[lane * 5 + 2] * wscale;
    const float wi3 = W_ih[lane * 5 + 3] * wscale;
    const float wi4 = W_ih[lane * 5 + 4] * wscale;
    const half2v wip01 = pk16(wi0, wi1);
    const half2v wip23 = pk16(wi2, wi3);

    // k=0..3 recurrent weights in f32 (readlane path, chain head).
    const float wh0 = W_hh[lane * 16 + 0] * wscale;
    const float wh1 = W_hh[lane * 16 + 1] * wscale;
    const float wh2 = W_hh[lane * 16 + 2] * wscale;
    const float wh3 = W_hh[lane * 16 + 3] * wscale;
    // k=4..15 as f16 pairs (bpermute path, consumed last).
    half2v whp[8];
#pragma unroll
    for (int k = 2; k < 8; ++k)
        whp[k] = pk16(W_hh[lane * 16 + 2 * k] * wscale,
                      W_hh[lane * 16 + 2 * k + 1] * wscale);
    const float bias = (b_ih[lane] + b_hh[lane]) * wscale;

    float fw[16];
#pragma unroll
    for (int k = 0; k < 16; ++k) fw[k] = fc_w[k];
    const float fcb = fc_b[0];

    __shared__ __align__(16) unsigned xp[512];  // 2 halves x 64 rows x 16B
    __shared__ float ls_h[64 * 17];

    const float* __restrict__ xb = x   + (size_t)b * T * 5;
    float*       __restrict__ yb = out + (size_t)b * T;
    const int NC = T >> 6;

    // Prologue: pack chunk 0; chunk 1 raw rows in rp.
    float rp[5];
    {
        const float* g0 = xb + lane * 5;
        uint4 v;
        v.x = h2u(pk16(g0[0], g0[1]));
        v.y = h2u(pk16(g0[2], g0[3]));
        v.z = __float_as_uint(g0[4]);
        v.w = 0u;
        *(uint4*)&xp[lane * 4] = v;
        if (NC > 1) {
            const float* g1 = xb + 320 + lane * 5;
#pragma unroll
            for (int k = 0; k < 5; ++k) rp[k] = g1[k];
        } else {
#pragma unroll
            for (int k = 0; k < 5; ++k) rp[k] = 0.0f;
        }
    }

    uint4 sv0 = *(const uint4*)&xp[0];
    uint4 sv1 = *(const uint4*)&xp[4];

    float C = 0.0f, h = 0.0f;              // C = -2log2e * c (pre-scaled)
    float rl0 = 0.0f, rl1 = 0.0f, rl2 = 0.0f, rl3 = 0.0f;   // h[0..3] f32
    unsigned hp2, hp3, hp4, hp5, hp6, hp7;                  // h pairs 2..7
    hp2 = hp3 = hp4 = hp5 = hp6 = hp7 = 0u;

    // Uniform bpermute byte indices: pair p from lane 2p.
    const int bx2 = 16, bx3 = 24, bx4 = 32, bx5 = 40, bx6 = 48, bx7 = 56;

#define LSTM_STEP(SV, TP)                                                     \
    {                                                                         \
        const int tpv = (TP);                                                 \
        /* independent x seeds + slot reload first (cover bp latency) */      \
        float a0 = dot2(u2h(SV.x), wip01, bias);                              \
        float a1 = dot2(u2h(SV.y), wip23, __uint_as_float(SV.z) * wi4);       \
        const int w_ = (base + (tpv + 2) * 4) & 511;                          \
        SV = *(const uint4*)&xp[w_];                                          \
        /* chain head: k=0..3 from f32 readlanes */                           \
        a0 = fmaf(rl0, wh0, a0);                                              \
        a0 = fmaf(rl1, wh1, a0);                                              \
        a1 = fmaf(rl2, wh2, a1);                                              \
        a1 = fmaf(rl3, wh3, a1);                                              \
        /* tail: k=4..15 from bpermute f16 pairs */                           \
        float a2 = dot2(u2h(hp2), whp[2], 0.0f);                              \
        a2 = dot2(u2h(hp3), whp[3], a2);                                      \
        a2 = dot2(u2h(hp4), whp[4], a2);                                      \
        float a3 = dot2(u2h(hp5), whp[5], 0.0f);                              \
        a3 = dot2(u2h(hp6), whp[6], a3);                                      \
        a3 = dot2(u2h(hp7), whp[7], a3);                                      \
        const float pre = (a0 + a2) + (a1 + a3);                              \
        const float e_  = __builtin_amdgcn_exp2f(pre);                        \
        const float s_  = __builtin_amdgcn_rcpf(1.0f + e_);                   \
        const float act = fmaf(post_m, s_, post_a);                           \
        float A1 = act, B1 = act;                                             \
        plswap32(A1, B1);                                                     \
        float iv = A1, fv = A1;                                               \
        plswap16(iv, fv);                                                     \
        float gv = B1, ov = B1;                                               \
        plswap16(gv, ov);                                                     \
        const float ivg = iv * gv;                                            \
        C = fmaf(fv, C, ivg * KN2);                                           \
        const float e2 = __builtin_amdgcn_exp2f(C);                           \
        const float r2 = __builtin_amdgcn_rcpf(1.0f + e2);                    \
        const float ov2 = ov + ov;                                            \
        h = fmaf(ov2, r2, -ov);                                               \
        ls_h[tpv * 17 + jj] = h;                                              \
        /* broadcast: readlanes first (chain head of t+1), then pack+bps */   \
        rl0 = readlane_f(h, 0);                                               \
        rl1 = readlane_f(h, 1);                                               \
        rl2 = readlane_f(h, 2);                                               \
        rl3 = readlane_f(h, 3);                                               \
        const float hsw   = quad_swap1(h);                                    \
        const unsigned hu = h2u(pk16(h, hsw));                                \
        const int hui = (int)hu;                                              \
        hp2 = (unsigned)__builtin_amdgcn_ds_bpermute(bx2, hui);               \
        hp3 = (unsigned)__builtin_amdgcn_ds_bpermute(bx3, hui);               \
        hp4 = (unsigned)__builtin_amdgcn_ds_bpermute(bx4, hui);               \
        hp5 = (unsigned)__builtin_amdgcn_ds_bpermute(bx5, hui);               \
        hp6 = (unsigned)__builtin_amdgcn_ds_bpermute(bx6, hui);               \
        hp7 = (unsigned)__builtin_amdgcn_ds_bpermute(bx7, hui);               \
    }

    for (int n = 0; n < NC; ++n) {
        const int base = (n & 1) * 256;

        if (n + 1 < NC) {
            const int dh = ((n + 1) & 1) * 256;
            uint4 v;
            v.x = h2u(pk16(rp[0], rp[1]));
            v.y = h2u(pk16(rp[2], rp[3]));
            v.z = __float_as_uint(rp[4]);
            v.w = 0u;
            *(uint4*)&xp[dh + lane * 4] = v;
            if (n + 2 < NC) {
                const float* g2 = xb + (size_t)(n + 2) * 320 + lane * 5;
#pragma unroll
                for (int k = 0; k < 5; ++k) rp[k] = g2[k];
            }
        }

        for (int tp = 0; tp < 64; tp += 4) {
            LSTM_STEP(sv0, tp);
            LSTM_STEP(sv1, tp + 1);
            LSTM_STEP(sv0, tp + 2);
            LSTM_STEP(sv1, tp + 3);
        }

        float y = fcb;
#pragma unroll
        for (int k = 0; k < 16; ++k) y = fmaf(ls_h[lane * 17 + k], fw[k], y);
        yb[(n << 6) + lane] = y;
    }
#undef LSTM_STEP
}

extern "C" void kernel_launch(void* const* d_in, const int* in_sizes, int n_in,
                              void* d_out, int out_size, void* d_ws, size_t ws_size,
                              hipStream_t stream) {
    const float* x    = (const float*)d_in[0];
    const float* W_ih = (const float*)d_in[1];
    const float* W_hh = (const float*)d_in[2];
    const float* b_ih = (const float*)d_in[3];
    const float* b_hh = (const float*)d_in[4];
    const float* fc_w = (const float*)d_in[5];
    const float* fc_b = (const float*)d_in[6];
    float* out = (float*)d_out;

    const int B = 256;
    const int T = out_size / B;   // 8192

    lstm_fused<<<dim3(B), dim3(64), 0, stream>>>(
        x, W_ih, W_hh, b_ih, b_hh, fc_w, fc_b, out, T);
}